// Round 2
// baseline (984.815 us; speedup 1.0000x reference)
//
#include <hip/hip_runtime.h>

#define Bn 8
#define Cn 64
#define Fn 256
#define Tn 512
#define FT (Fn*Tn)          // 131072
#define NPIX (Bn*Fn*Tn)     // 1048576
#define NTOT (Bn*Cn*Fn*Tn)  // 67108864

// ws float offsets
#define WS_MT    0               // [B*C*T] 262144  SUM over F (atomic, memset to 0)
#define WS_MF    262144          // [B*C*F] 131072  SUM over T
#define WS_ZT    393216          // [B*C*T]
#define WS_ZFW   655360          // [B*C*F]  (zf * wc[c])
#define WS_WCAT  786432          // [64][128]: row c: [0:64]=Wb[c][k], [64:128]=W2[c][k]
#define WS_P     794624          // [64][24] prefix sums of wc2 over thresholds (P[k][L])
#define WS_THR   796160          // [32]
#define WS_SUM   796192          // [64]
#define WS_SUMSQ 796256          // [64]
#define WS_SCALE 796320          // [64]
#define WS_SHIFT 796384          // [64]

// ---------------- K1: fused row/col sums, 8 F-chunks per slab ----------------
__global__ __launch_bounds__(256) void k1_sums(const float* __restrict__ x,
                                               float* __restrict__ ws) {
    const int bx = blockIdx.x;                   // 4096 blocks
    const int slab = bx >> 3, chunk = bx & 7;    // slab = b*64+c
    const int wave = threadIdx.x >> 6, lane = threadIdx.x & 63;
    const float4* x4 = (const float4*)x + (size_t)slab * (FT / 4) + chunk * 32 * 128;
    __shared__ float lcs[4 * 512];
    float4 cs0 = {0.f,0.f,0.f,0.f}, cs1 = {0.f,0.f,0.f,0.f};
    #pragma unroll
    for (int r = 0; r < 8; ++r) {
        const int row = wave * 8 + r;            // 0..31 within chunk
        float4 v0 = x4[row * 128 + lane];
        float4 v1 = x4[row * 128 + 64 + lane];
        cs0.x += v0.x; cs0.y += v0.y; cs0.z += v0.z; cs0.w += v0.w;
        cs1.x += v1.x; cs1.y += v1.y; cs1.z += v1.z; cs1.w += v1.w;
        float rs = (v0.x + v0.y) + (v0.z + v0.w) + (v1.x + v1.y) + (v1.z + v1.w);
        #pragma unroll
        for (int m = 1; m < 64; m <<= 1) rs += __shfl_xor(rs, m, 64);
        if (lane == 0) ws[WS_MF + slab * Fn + chunk * 32 + row] = rs;   // SUM over T
    }
    ((float4*)lcs)[wave * 128 + lane] = cs0;
    ((float4*)lcs)[wave * 128 + 64 + lane] = cs1;
    __syncthreads();
    for (int t = threadIdx.x; t < 512; t += 256) {
        float s = lcs[t] + lcs[512 + t] + lcs[1024 + t] + lcs[1536 + t];
        atomicAdd(&ws[WS_MT + slab * Tn + t], s);   // SUM over F
    }
}

// ---------------- K2: channel MLPs + weight folding / tables ----------------
__global__ __launch_bounds__(256) void k2_mlp_prep(
    const float* __restrict__ w1, const float* __restrict__ b1,
    const float* __restrict__ w2, const float* __restrict__ b2,
    const float* __restrict__ wc, const float* __restrict__ bc2,
    const float* __restrict__ wo, const float* __restrict__ wc2,
    float* __restrict__ ws) {
    const int blk = blockIdx.x;
    if (blk < 1536) {
        const int wave = threadIdx.x >> 6, c = threadIdx.x & 63;
        const bool is_t = (blk < 1024);
        float m; int b, l;
        if (is_t) {                       // zt positions: p = b*512 + t
            const int p = blk * 4 + wave;
            b = p >> 9; l = p & 511;
            m = ws[WS_MT + (b * 64 + c) * Tn + l] * (1.0f / Fn);
        } else {                          // zf positions: p = b*256 + f
            const int p = (blk - 1024) * 4 + wave;
            b = p >> 8; l = p & 255;
            m = ws[WS_MF + (b * 64 + c) * Fn + l] * (1.0f / Tn);
        }
        float acc = b2[c];
        #pragma unroll
        for (int o = 0; o < 5; ++o) {
            float v = w1[o * 64 + c] * m;
            #pragma unroll
            for (int mm = 1; mm < 64; mm <<= 1) v += __shfl_xor(v, mm, 64);
            const float h = fmaxf(v + b1[o], 0.0f);
            acc = fmaf(w2[c * 5 + o], h, acc);
        }
        const float sg = 1.0f / (1.0f + expf(-acc));
        if (is_t) ws[WS_ZT  + (b * 64 + c) * Tn + l] = sg;
        else      ws[WS_ZFW + (b * 64 + c) * Fn + l] = sg * wc[c];
    } else {
        const int tid = threadIdx.x;
        // folded weights, [c][128]: wcat[c][k] = wo1[c][k] + wo2[c][k]*bc2[k]; wcat[c][64+k] = wo2[c][k]
        for (int i = tid; i < 64 * 128; i += 256) {
            const int c = i >> 7, j = i & 127;
            float v;
            if (j < 64) v = wo[c * 128 + j] + wo[c * 128 + 64 + j] * bc2[j];
            else        v = wo[c * 128 + j];
            ws[WS_WCAT + i] = v;
        }
        // P prefix sums over thresholds: P[k][L] = sum_{i<L} wc2[k][i]
        for (int c = tid; c < 64; c += 256) {
            float a = 0.f;
            ws[WS_P + c * 24 + 0] = 0.f;
            for (int K = 1; K <= 23; ++K) { a += wc2[c * 23 + K - 1]; ws[WS_P + c * 24 + K] = a; }
        }
        if (tid == 0) {  // exact replication of np.cumsum(np.arange(1,24)/300.0) -> fp32
            double a = 0.0;
            for (int i = 1; i <= 23; ++i) { a += (double)i / 300.0; ws[WS_THR + i - 1] = (float)a; }
            for (int i = 23; i < 32; ++i) ws[WS_THR + i] = 1e30f;
        }
        if (tid < 64) { ws[WS_SUM + tid] = 0.f; ws[WS_SUMSQ + tid] = 0.f; }
    }
}

// ---------------- K4: main fused pass + BN stats ----------------
__global__ __launch_bounds__(256, 2) void k4_main(
    const float* __restrict__ x, const float* __restrict__ wsc,
    const float* __restrict__ bc, const float* __restrict__ bo,
    float* __restrict__ out, float* __restrict__ ws) {
    const int blk = blockIdx.x;           // 4096 blocks
    const int b = blk >> 9;
    const int rem = blk & 511;
    const int f = rem >> 1;
    const int tid = threadIdx.x;
    const int t = ((rem & 1) << 8) + tid;

    __shared__ float Pl[64 * 24];
    __shared__ float tbuf[16][257];
    __shared__ float ssum[64], ssq[64];
    for (int i = tid; i < 64 * 24; i += 256) Pl[i] = wsc[WS_P + i];
    if (tid < 64) { ssum[tid] = 0.f; ssq[tid] = 0.f; }
    __syncthreads();

    // attention map value (per pixel)
    const float* zfw = wsc + WS_ZFW + b * (Cn * Fn) + f;  // block-uniform stride reads
    const float* zt  = wsc + WS_ZT  + b * (Cn * Tn) + t;  // lane-coalesced
    float am = bc[0];
    #pragma unroll
    for (int c = 0; c < 64; ++c) am = fmaf(zfw[c * Fn], zt[c * Tn], am);

    int L = 0;
    #pragma unroll
    for (int i = 0; i < 23; ++i) L += (am > wsc[WS_THR + i]) ? 1 : 0;

    const int pix = b * (Cn * FT) + f * Tn + t;   // base at c=0
    const float* xp = x + pix;
    float* op = out + pix;
    const float* wcat = wsc + WS_WCAT;

    // prefetch the pixel's channel column and its thresholded-scaled twin
    float xv[64], y2v[64];
    #pragma unroll
    for (int k = 0; k < 64; ++k) xv[k] = xp[k * FT];
    #pragma unroll
    for (int k = 0; k < 64; ++k) y2v[k] = am * Pl[k * 24 + L] * xv[k];

    #pragma unroll 1
    for (int cb = 0; cb < 64; cb += 16) {
        #pragma unroll
        for (int cc = 0; cc < 16; ++cc) {
            const int c = cb + cc;
            const float* wr = wcat + c * 128;     // wave-uniform -> scalar loads
            float acc = bo[c];
            #pragma unroll
            for (int k = 0; k < 64; ++k)
                acc = fmaf(wr[64 + k], y2v[k], fmaf(wr[k], xv[k], acc));
            op[c * FT] = acc;
            tbuf[cc][tid] = acc;
        }
        __syncthreads();
        {   // reduce this 16-channel chunk: per-channel sum/sumsq over 256 threads
            const int ch = tid & 15, g = tid >> 4;
            float s = 0.f, q = 0.f;
            #pragma unroll
            for (int i2 = 0; i2 < 16; ++i2) {
                const float v = tbuf[ch][g * 16 + i2];
                s += v; q = fmaf(v, v, q);
            }
            atomicAdd(&ssum[cb + ch], s);
            atomicAdd(&ssq[cb + ch], q);
        }
        __syncthreads();
    }
    if (tid < 64) {
        atomicAdd(&ws[WS_SUM + tid], ssum[tid]);
        atomicAdd(&ws[WS_SUMSQ + tid], ssq[tid]);
    }
}

// ---------------- K6: fold BN stats into per-channel scale/shift ----------------
__global__ void k6_fin(const float* __restrict__ gamma, const float* __restrict__ beta,
                       float* __restrict__ ws) {
    const int c = threadIdx.x;
    if (c < 64) {
        const float n = (float)NPIX;
        const float mu = ws[WS_SUM + c] / n;
        const float var = ws[WS_SUMSQ + c] / n - mu * mu;
        const float sc = gamma[c] * rsqrtf(var + 1e-5f);
        ws[WS_SCALE + c] = sc;
        ws[WS_SHIFT + c] = beta[c] - mu * sc;
    }
}

// ---------------- K7: in-place normalize + ReLU ----------------
__global__ __launch_bounds__(256) void k7_norm(float* __restrict__ o,
                                               const float* __restrict__ ws) {
    const int n4 = NTOT / 4;                    // 16777216
    for (int i = blockIdx.x * 256 + threadIdx.x; i < n4; i += gridDim.x * 256) {
        const int c = (i >> 15) & 63;           // 32768 float4 per (b,c) slab
        const float sc = ws[WS_SCALE + c], sh = ws[WS_SHIFT + c];
        float4 v = ((float4*)o)[i];
        v.x = fmaxf(fmaf(v.x, sc, sh), 0.f);
        v.y = fmaxf(fmaf(v.y, sc, sh), 0.f);
        v.z = fmaxf(fmaf(v.z, sc, sh), 0.f);
        v.w = fmaxf(fmaf(v.w, sc, sh), 0.f);
        ((float4*)o)[i] = v;
    }
}

extern "C" void kernel_launch(void* const* d_in, const int* in_sizes, int n_in,
                              void* d_out, int out_size, void* d_ws, size_t ws_size,
                              hipStream_t stream) {
    const float* x     = (const float*)d_in[0];
    const float* w1    = (const float*)d_in[1];
    const float* b1    = (const float*)d_in[2];
    const float* w2    = (const float*)d_in[3];
    const float* b2    = (const float*)d_in[4];
    const float* wc    = (const float*)d_in[5];
    const float* bc    = (const float*)d_in[6];
    const float* wc2   = (const float*)d_in[7];
    const float* bc2   = (const float*)d_in[8];
    const float* wo    = (const float*)d_in[9];
    const float* bo    = (const float*)d_in[10];
    const float* gamma = (const float*)d_in[11];
    const float* beta  = (const float*)d_in[12];
    float* out = (float*)d_out;
    float* ws  = (float*)d_ws;

    hipMemsetAsync(ws + WS_MT, 0, Bn * Cn * Tn * sizeof(float), stream);  // zero F-sum accumulators
    k1_sums<<<4096, 256, 0, stream>>>(x, ws);
    k2_mlp_prep<<<1537, 256, 0, stream>>>(w1, b1, w2, b2, wc, bc2, wo, wc2, ws);
    k4_main<<<4096, 256, 0, stream>>>(x, ws, bc, bo, out, ws);
    k6_fin<<<1, 64, 0, stream>>>(gamma, beta, ws);
    k7_norm<<<8192, 256, 0, stream>>>(out, ws);
}

// Round 3
// 718.474 us; speedup vs baseline: 1.3707x; 1.3707x over previous
//
#include <hip/hip_runtime.h>

#define Bn 8
#define Cn 64
#define Fn 256
#define Tn 512
#define FT (Fn*Tn)          // 131072
#define NPIX (Bn*Fn*Tn)     // 1048576
#define NTOT (Bn*Cn*Fn*Tn)  // 67108864

// ws float offsets
#define WS_MT    0               // [B*C*T] SUM over F (atomic, memset to 0)
#define WS_MF    262144          // [B*C*F] SUM over T
#define WS_ZT    393216          // [B*C*T] sigmoid
#define WS_ZFW   655360          // [B*C*F] sigmoid * wc[c]
#define WS_P     786432          // [64][24] prefix sums of wc2 (P[k][L])
#define WS_THR   787968          // [32]
#define WS_AHI   788000          // 8192 bf16 (as 4096 floats): A hi plane, frag-linear
#define WS_ALO   792096          // 8192 bf16: A lo plane
#define WS_PSH   796192          // [64 shards][128] partial sums (zeroed in k2)
#define WS_SCALE 804384          // [64]
#define WS_SHIFT 804448          // [64]

typedef __attribute__((ext_vector_type(8))) short bf16x8;
typedef __attribute__((ext_vector_type(4))) float f32x4;

__device__ __forceinline__ void split2(float x, unsigned short& h, unsigned short& l) {
    unsigned u = __builtin_bit_cast(unsigned, x);
    unsigned r = u + 0x7FFFu + ((u >> 16) & 1u);
    h = (unsigned short)(r >> 16);
    float hf = __builtin_bit_cast(float, r & 0xFFFF0000u);
    float lo = x - hf;
    unsigned ul = __builtin_bit_cast(unsigned, lo);
    unsigned rl = ul + 0x7FFFu + ((ul >> 16) & 1u);
    l = (unsigned short)(rl >> 16);
}

// ---------------- K1: fused row/col sums, 8 F-chunks per slab ----------------
__global__ __launch_bounds__(256) void k1_sums(const float* __restrict__ x,
                                               float* __restrict__ ws) {
    const int bx = blockIdx.x;                   // 4096 blocks
    const int slab = bx >> 3, chunk = bx & 7;    // slab = b*64+c
    const int wave = threadIdx.x >> 6, lane = threadIdx.x & 63;
    const float4* x4 = (const float4*)x + (size_t)slab * (FT / 4) + chunk * 32 * 128;
    __shared__ float lcs[4 * 512];
    float4 cs0 = {0.f,0.f,0.f,0.f}, cs1 = {0.f,0.f,0.f,0.f};
    #pragma unroll
    for (int r = 0; r < 8; ++r) {
        const int row = wave * 8 + r;            // 0..31 within chunk
        float4 v0 = x4[row * 128 + lane];
        float4 v1 = x4[row * 128 + 64 + lane];
        cs0.x += v0.x; cs0.y += v0.y; cs0.z += v0.z; cs0.w += v0.w;
        cs1.x += v1.x; cs1.y += v1.y; cs1.z += v1.z; cs1.w += v1.w;
        float rs = (v0.x + v0.y) + (v0.z + v0.w) + (v1.x + v1.y) + (v1.z + v1.w);
        #pragma unroll
        for (int m = 1; m < 64; m <<= 1) rs += __shfl_xor(rs, m, 64);
        if (lane == 0) ws[WS_MF + slab * Fn + chunk * 32 + row] = rs;   // SUM over T
    }
    ((float4*)lcs)[wave * 128 + lane] = cs0;
    ((float4*)lcs)[wave * 128 + 64 + lane] = cs1;
    __syncthreads();
    for (int t = threadIdx.x; t < 512; t += 256) {
        float s = lcs[t] + lcs[512 + t] + lcs[1024 + t] + lcs[1536 + t];
        atomicAdd(&ws[WS_MT + slab * Tn + t], s);   // SUM over F
    }
}

// ---------------- K2: channel MLPs + weight split / tables ----------------
__global__ __launch_bounds__(256) void k2_mlp_prep(
    const float* __restrict__ w1, const float* __restrict__ b1,
    const float* __restrict__ w2, const float* __restrict__ b2,
    const float* __restrict__ wc, const float* __restrict__ bc2,
    const float* __restrict__ wo, const float* __restrict__ wc2,
    float* __restrict__ ws) {
    const int blk = blockIdx.x;
    if (blk < 1536) {
        const int wave = threadIdx.x >> 6, c = threadIdx.x & 63;
        const bool is_t = (blk < 1024);
        float m; int b, l;
        if (is_t) {                       // zt positions: p = b*512 + t
            const int p = blk * 4 + wave;
            b = p >> 9; l = p & 511;
            m = ws[WS_MT + (b * 64 + c) * Tn + l] * (1.0f / Fn);
        } else {                          // zf positions: p = b*256 + f
            const int p = (blk - 1024) * 4 + wave;
            b = p >> 8; l = p & 255;
            m = ws[WS_MF + (b * 64 + c) * Fn + l] * (1.0f / Tn);
        }
        float acc = b2[c];
        #pragma unroll
        for (int o = 0; o < 5; ++o) {
            float v = w1[o * 64 + c] * m;
            #pragma unroll
            for (int mm = 1; mm < 64; mm <<= 1) v += __shfl_xor(v, mm, 64);
            const float h = fmaxf(v + b1[o], 0.0f);
            acc = fmaf(w2[c * 5 + o], h, acc);
        }
        const float sg = 1.0f / (1.0f + expf(-acc));
        if (is_t) ws[WS_ZT  + (b * 64 + c) * Tn + l] = sg;
        else      ws[WS_ZFW + (b * 64 + c) * Fn + l] = sg * wc[c];
    } else {
        const int tid = threadIdx.x;
        // A (64 x 128) = [Wb | W2], split to bf16 hi/lo, frag-linear layout:
        // chunk = (k>>5)*4 + (m>>4); within: quad=(k>>3)&3, m16=m&15, j=k&7
        unsigned short* AH = (unsigned short*)(ws + WS_AHI);
        unsigned short* AL = (unsigned short*)(ws + WS_ALO);
        for (int i = tid; i < 8192; i += 256) {
            const int chunk = i >> 9, within = i & 511;
            const int quad = within >> 7, m16 = (within >> 3) & 15, j = within & 7;
            const int m = (chunk & 3) * 16 + m16;
            const int k = (chunk >> 2) * 32 + quad * 8 + j;
            float v;
            if (k < 64) v = wo[m * 128 + k] + wo[m * 128 + 64 + k] * bc2[k];
            else        v = wo[m * 128 + k];   // = wo2[m][k-64]
            unsigned short h, l;
            split2(v, h, l);
            AH[i] = h; AL[i] = l;
        }
        // P prefix sums: P[k][L] = sum_{i<L} wc2[k][i]
        for (int c = tid; c < 64; c += 256) {
            float a = 0.f;
            ws[WS_P + c * 24 + 0] = 0.f;
            for (int K = 1; K <= 23; ++K) { a += wc2[c * 23 + K - 1]; ws[WS_P + c * 24 + K] = a; }
        }
        if (tid == 0) {  // exact replication of np.cumsum(np.arange(1,24)/300.0) -> fp32
            double a = 0.0;
            for (int i = 1; i <= 23; ++i) { a += (double)i / 300.0; ws[WS_THR + i - 1] = (float)a; }
            for (int i = 23; i < 32; ++i) ws[WS_THR + i] = 1e30f;
        }
        for (int i = tid; i < 8192; i += 256) ws[WS_PSH + i] = 0.f;   // zero stat shards
    }
}

// ---------------- K4: MFMA main pass (tile: 64 ch x 64 px, K=128) + BN stats ----------------
__global__ __launch_bounds__(256) void k4_main(
    const float* __restrict__ x, const float* __restrict__ wsc,
    const float* __restrict__ bc, const float* __restrict__ bo,
    float* __restrict__ out, float* __restrict__ ws) {
    __shared__ __align__(16) short Bhi[16 * 512];   // 16 KB, frag-linear
    __shared__ __align__(16) short Blo[16 * 512];   // 16 KB
    __shared__ float Pl[64 * 24];                   // 6 KB
    __shared__ float sstat[128];

    const int tid = threadIdx.x;
    const int blk = blockIdx.x;                // 16384 blocks
    const int b = blk >> 11;
    const int rem = blk & 2047;
    const int f = rem >> 3;
    const int t0 = (rem & 7) << 6;

    for (int i = tid; i < 1536; i += 256) Pl[i] = wsc[WS_P + i];
    if (tid < 128) sstat[tid] = 0.f;

    const int t_local = tid & 63, kg = tid >> 6;
    const int t = t0 + t_local;
    const int nfrag = t_local >> 4, n16 = t_local & 15;

    // --- per-pixel attention value am and threshold level L ---
    const float* zfw = wsc + WS_ZFW + b * (Cn * Fn) + f;  // block-uniform
    const float* zt  = wsc + WS_ZT  + b * (Cn * Tn) + t;  // lane-coalesced
    float am = bc[0];
    #pragma unroll
    for (int c = 0; c < 64; ++c) am = fmaf(zfw[c * Fn], zt[c * Tn], am);
    int L = 0;
    #pragma unroll
    for (int i = 0; i < 23; ++i) L += (am > wsc[WS_THR + i]) ? 1 : 0;

    __syncthreads();   // Pl ready

    // --- stage B = [X; G] as bf16 hi/lo, frag-linear ---
    const float* xb = x + (size_t)b * (Cn * FT) + f * Tn + t;   // + k*FT
    #pragma unroll
    for (int g = 0; g < 2; ++g) {
        const int k8 = (kg + g * 4) << 3;          // 0,8,...,56
        float xv[8];
        #pragma unroll
        for (int i = 0; i < 8; ++i) xv[i] = xb[(size_t)(k8 + i) * FT];
        unsigned ph[4], pl[4];
        #pragma unroll
        for (int i = 0; i < 4; ++i) {
            unsigned short h0, l0, h1, l1;
            split2(xv[2 * i], h0, l0); split2(xv[2 * i + 1], h1, l1);
            ph[i] = (unsigned)h0 | ((unsigned)h1 << 16);
            pl[i] = (unsigned)l0 | ((unsigned)l1 << 16);
        }
        const int cka = ((k8 >> 5) * 4 + nfrag) * 512 + ((k8 >> 3) & 3) * 128 + n16 * 8;
        *(int4*)&Bhi[cka] = make_int4(ph[0], ph[1], ph[2], ph[3]);
        *(int4*)&Blo[cka] = make_int4(pl[0], pl[1], pl[2], pl[3]);
        // G row: global K index 64+k -> chunk offset +8 -> +4096 shorts
        float gv[8];
        #pragma unroll
        for (int i = 0; i < 8; ++i) gv[i] = am * Pl[(k8 + i) * 24 + L] * xv[i];
        #pragma unroll
        for (int i = 0; i < 4; ++i) {
            unsigned short h0, l0, h1, l1;
            split2(gv[2 * i], h0, l0); split2(gv[2 * i + 1], h1, l1);
            ph[i] = (unsigned)h0 | ((unsigned)h1 << 16);
            pl[i] = (unsigned)l0 | ((unsigned)l1 << 16);
        }
        *(int4*)&Bhi[cka + 4096] = make_int4(ph[0], ph[1], ph[2], ph[3]);
        *(int4*)&Blo[cka + 4096] = make_int4(pl[0], pl[1], pl[2], pl[3]);
    }
    __syncthreads();

    // --- MFMA: wave w owns channels [w*16, w*16+16); 4 n-frags; K = 128 ---
    const int lane = tid & 63, w = tid >> 6;
    const int quad = lane >> 4, l16 = lane & 15;
    const short* AH = (const short*)(wsc + WS_AHI);
    const short* AL = (const short*)(wsc + WS_ALO);

    f32x4 acc[4];
    const float4 bo4 = *(const float4*)&bo[w * 16 + quad * 4];
    #pragma unroll
    for (int nf = 0; nf < 4; ++nf) { acc[nf].x = bo4.x; acc[nf].y = bo4.y; acc[nf].z = bo4.z; acc[nf].w = bo4.w; }

    #pragma unroll
    for (int ks = 0; ks < 4; ++ks) {
        const int ao = (ks * 4 + w) * 512 + quad * 128 + l16 * 8;
        const bf16x8 ah = *(const bf16x8*)(AH + ao);
        const bf16x8 al = *(const bf16x8*)(AL + ao);
        #pragma unroll
        for (int nf = 0; nf < 4; ++nf) {
            const int bof = (ks * 4 + nf) * 512 + quad * 128 + l16 * 8;
            const bf16x8 bh = *(const bf16x8*)&Bhi[bof];
            const bf16x8 bl = *(const bf16x8*)&Blo[bof];
            acc[nf] = __builtin_amdgcn_mfma_f32_16x16x32_bf16(ah, bh, acc[nf], 0, 0, 0);
            acc[nf] = __builtin_amdgcn_mfma_f32_16x16x32_bf16(ah, bl, acc[nf], 0, 0, 0);
            acc[nf] = __builtin_amdgcn_mfma_f32_16x16x32_bf16(al, bh, acc[nf], 0, 0, 0);
        }
    }

    // --- write O (fp32) + fused BN partial stats ---
    float* ob = out + (size_t)b * (Cn * FT) + f * Tn + t0;
    #pragma unroll
    for (int r = 0; r < 4; ++r) {
        const int c = w * 16 + quad * 4 + r;
        float vs = 0.f, vq = 0.f;
        #pragma unroll
        for (int nf = 0; nf < 4; ++nf) {
            const float v = acc[nf][r];
            ob[(size_t)c * FT + nf * 16 + l16] = v;
            vs += v; vq = fmaf(v, v, vq);
        }
        #pragma unroll
        for (int m = 1; m < 16; m <<= 1) { vs += __shfl_xor(vs, m); vq += __shfl_xor(vq, m); }
        if (l16 == 0) { sstat[c] = vs; sstat[64 + c] = vq; }
    }
    __syncthreads();
    if (tid < 128) atomicAdd(&ws[WS_PSH + (blk & 63) * 128 + tid], sstat[tid]);
}

// ---------------- K6: reduce shards -> per-channel scale/shift ----------------
__global__ void k6_fin(const float* __restrict__ gamma, const float* __restrict__ beta,
                       float* __restrict__ ws) {
    const int c = threadIdx.x;
    if (c < 64) {
        float s = 0.f, q = 0.f;
        for (int sh = 0; sh < 64; ++sh) {
            s += ws[WS_PSH + sh * 128 + c];
            q += ws[WS_PSH + sh * 128 + 64 + c];
        }
        const float n = (float)NPIX;
        const float mu = s / n;
        const float var = q / n - mu * mu;
        const float sc = gamma[c] * rsqrtf(var + 1e-5f);
        ws[WS_SCALE + c] = sc;
        ws[WS_SHIFT + c] = beta[c] - mu * sc;
    }
}

// ---------------- K7: in-place normalize + ReLU (slab-chunked, uniform scale) ----------------
__global__ __launch_bounds__(256) void k7_norm(float* __restrict__ o,
                                               const float* __restrict__ ws) {
    const int blk = blockIdx.x;                 // 16384 blocks
    const int slab = blk >> 5, chunk = blk & 31;
    const int c = slab & 63;
    const float sc = ws[WS_SCALE + c], sh = ws[WS_SHIFT + c];
    float4* o4 = (float4*)o + (size_t)slab * (FT / 4) + chunk * 1024;
    #pragma unroll
    for (int i = 0; i < 4; ++i) {
        float4 v = o4[i * 256 + threadIdx.x];
        v.x = fmaxf(fmaf(v.x, sc, sh), 0.f);
        v.y = fmaxf(fmaf(v.y, sc, sh), 0.f);
        v.z = fmaxf(fmaf(v.z, sc, sh), 0.f);
        v.w = fmaxf(fmaf(v.w, sc, sh), 0.f);
        o4[i * 256 + threadIdx.x] = v;
    }
}

extern "C" void kernel_launch(void* const* d_in, const int* in_sizes, int n_in,
                              void* d_out, int out_size, void* d_ws, size_t ws_size,
                              hipStream_t stream) {
    const float* x     = (const float*)d_in[0];
    const float* w1    = (const float*)d_in[1];
    const float* b1    = (const float*)d_in[2];
    const float* w2    = (const float*)d_in[3];
    const float* b2    = (const float*)d_in[4];
    const float* wc    = (const float*)d_in[5];
    const float* bc    = (const float*)d_in[6];
    const float* wc2   = (const float*)d_in[7];
    const float* bc2   = (const float*)d_in[8];
    const float* wo    = (const float*)d_in[9];
    const float* bo    = (const float*)d_in[10];
    const float* gamma = (const float*)d_in[11];
    const float* beta  = (const float*)d_in[12];
    float* out = (float*)d_out;
    float* ws  = (float*)d_ws;

    hipMemsetAsync(ws + WS_MT, 0, Bn * Cn * Tn * sizeof(float), stream);  // zero F-sum accumulators
    k1_sums<<<4096, 256, 0, stream>>>(x, ws);
    k2_mlp_prep<<<1537, 256, 0, stream>>>(w1, b1, w2, b2, wc, bc2, wo, wc2, ws);
    k4_main<<<16384, 256, 0, stream>>>(x, ws, bc, bo, out, ws);
    k6_fin<<<1, 64, 0, stream>>>(gamma, beta, ws);
    k7_norm<<<16384, 256, 0, stream>>>(out, ws);
}